// Round 1
// baseline (1157.618 us; speedup 1.0000x reference)
//
#include <hip/hip_runtime.h>

#define E0     300000
#define E1     75000
#define NSRC0  50000
#define NDST0  20000
#define NDST1  5000
#define EMB    128
#define HID    256
#define NOUT   16

// ---------------- degree histograms (all four at once) ----------------
__global__ void deg_kernel(const int* __restrict__ src0, const int* __restrict__ dst0,
                           const int* __restrict__ src1, const int* __restrict__ dst1,
                           float* deg_out0, float* deg_in0, float* deg_out1, float* deg_in1) {
    int i = blockIdx.x * blockDim.x + threadIdx.x;
    if (i < E0) {
        atomicAdd(&deg_out0[src0[i]], 1.0f);
        atomicAdd(&deg_in0[dst0[i]], 1.0f);
    }
    if (i < E1) {
        atomicAdd(&deg_out1[src1[i]], 1.0f);
        atomicAdd(&deg_in1[dst1[i]], 1.0f);
    }
}

// ---------------- fused embedding mean + out-degree scale ----------------
// x0[node] = mean_{50 words} word_table[idx] * rsqrt(max(deg_out0[node],1))
__global__ void embed_kernel(const int* __restrict__ user_word,
                             const float* __restrict__ word_table,
                             const float* __restrict__ deg_out0,
                             float* __restrict__ x0) {
    int node = blockIdx.x;
    int t = threadIdx.x;               // 0..127 = feature dim
    __shared__ int idx[50];
    if (t < 50) idx[t] = user_word[node * 50 + t];
    __syncthreads();
    float acc = 0.0f;
    #pragma unroll 5
    for (int w = 0; w < 50; ++w)
        acc += word_table[idx[w] * EMB + t];
    float s = rsqrtf(fmaxf(deg_out0[node], 1.0f));
    x0[node * EMB + t] = acc * 0.02f * s;   // 0.02 = 1/50 (mean of equal-size means)
}

// ---------------- layer-1 edge scatter: agg1[dst] += x0[src] ----------------
// 32 lanes/edge, float4 per lane (coalesced gather, 4 scalar atomics)
__global__ void scatter1_kernel(const int* __restrict__ src0, const int* __restrict__ dst0,
                                const float* __restrict__ x0, float* agg1) {
    int t = blockIdx.x * blockDim.x + threadIdx.x;
    int e = t >> 5;
    if (e >= E0) return;
    int f = (t & 31) * 4;
    int s = src0[e], d = dst0[e];
    const float4 v = *(const float4*)(x0 + s * EMB + f);
    float* p = agg1 + d * EMB + f;
    atomicAdd(p + 0, v.x); atomicAdd(p + 1, v.y);
    atomicAdd(p + 2, v.z); atomicAdd(p + 3, v.w);
}

// ---------------- GEMM1: h1 = relu((agg1 * rsqrt(deg_in0)) @ W1 + b1) * rsqrt(deg_out1)
// 16 rows/block, 256 threads = 256 output cols; A-tile broadcast from LDS.
__global__ void gemm1_kernel(const float* __restrict__ agg1,
                             const float* __restrict__ deg_in0,
                             const float* __restrict__ deg_out1,
                             const float* __restrict__ W1, const float* __restrict__ b1,
                             float* __restrict__ h1) {
    __shared__ float A[16 * 128];
    __shared__ float s_in[16], s_out[16];
    int row0 = blockIdx.x * 16;
    int t = threadIdx.x;
    if (t < 16) {
        s_in[t]  = rsqrtf(fmaxf(deg_in0[row0 + t], 1.0f));
        s_out[t] = rsqrtf(fmaxf(deg_out1[row0 + t], 1.0f));
    }
    __syncthreads();
    for (int j = t; j < 16 * 128; j += 256) {
        int r = j >> 7;
        A[j] = agg1[(row0 + r) * 128 + (j & 127)] * s_in[r];
    }
    __syncthreads();
    float acc[16];
    #pragma unroll
    for (int r = 0; r < 16; ++r) acc[r] = 0.0f;
    for (int k = 0; k < 128; ++k) {
        float w = W1[k * 256 + t];          // coalesced across t
        #pragma unroll
        for (int r = 0; r < 16; ++r)
            acc[r] += A[r * 128 + k] * w;   // LDS broadcast (same addr all threads)
    }
    float bb = b1[t];
    #pragma unroll
    for (int r = 0; r < 16; ++r)
        h1[(row0 + r) * 256 + t] = fmaxf(acc[r] + bb, 0.0f) * s_out[r];
}

// ---------------- layer-2 edge scatter: agg2[dst] += h1[src] ----------------
// 64 lanes/edge, float4 per lane
__global__ void scatter2_kernel(const int* __restrict__ src1, const int* __restrict__ dst1,
                                const float* __restrict__ h1, float* agg2) {
    int t = blockIdx.x * blockDim.x + threadIdx.x;
    int e = t >> 6;
    if (e >= E1) return;
    int f = (t & 63) * 4;
    int s = src1[e], d = dst1[e];
    const float4 v = *(const float4*)(h1 + s * HID + f);
    float* p = agg2 + d * HID + f;
    atomicAdd(p + 0, v.x); atomicAdd(p + 1, v.y);
    atomicAdd(p + 2, v.z); atomicAdd(p + 3, v.w);
}

// ---------------- GEMM2: out = relu((agg2 * rsqrt(deg_in1)) @ W2 + b2) ----------------
// 16 rows/block, thread (r,c) = (t/16, t%16). A padded to 257 to kill bank conflicts.
__global__ void gemm2_kernel(const float* __restrict__ agg2,
                             const float* __restrict__ deg_in1,
                             const float* __restrict__ W2, const float* __restrict__ b2,
                             float* __restrict__ out) {
    __shared__ float A[16 * 257];
    __shared__ float Wl[256 * 16];
    __shared__ float s_in[16];
    int row0 = blockIdx.x * 16;
    int t = threadIdx.x;
    if (t < 16) {
        int row = row0 + t;
        s_in[t] = (row < NDST1) ? rsqrtf(fmaxf(deg_in1[row], 1.0f)) : 0.0f;
    }
    for (int j = t; j < 256 * 16; j += 256) Wl[j] = W2[j];
    __syncthreads();
    for (int j = t; j < 16 * 256; j += 256) {
        int r = j >> 8, k = j & 255;
        int row = row0 + r;
        A[r * 257 + k] = (row < NDST1) ? agg2[row * 256 + k] * s_in[r] : 0.0f;
    }
    __syncthreads();
    int r = t >> 4, c = t & 15;
    float acc = 0.0f;
    for (int k = 0; k < 256; ++k)
        acc += A[r * 257 + k] * Wl[k * 16 + c];
    int row = row0 + r;
    if (row < NDST1)
        out[row * NOUT + c] = fmaxf(acc + b2[c], 0.0f);
}

// ---------------- labels passthrough (int -> float) ----------------
__global__ void labels_kernel(const int* __restrict__ labels, float* __restrict__ out) {
    int i = blockIdx.x * blockDim.x + threadIdx.x;
    if (i < NDST1) out[NDST1 * NOUT + i] = (float)labels[i];
}

extern "C" void kernel_launch(void* const* d_in, const int* in_sizes, int n_in,
                              void* d_out, int out_size, void* d_ws, size_t ws_size,
                              hipStream_t stream) {
    const int*   user_word  = (const int*)d_in[0];
    const int*   labels     = (const int*)d_in[1];
    const int*   src0       = (const int*)d_in[2];
    const int*   dst0       = (const int*)d_in[3];
    const int*   src1       = (const int*)d_in[4];
    const int*   dst1       = (const int*)d_in[5];
    const float* word_table = (const float*)d_in[6];
    const float* W1         = (const float*)d_in[7];
    const float* b1         = (const float*)d_in[8];
    const float* W2         = (const float*)d_in[9];
    const float* b2         = (const float*)d_in[10];

    float* ws = (float*)d_ws;
    // layout (floats):
    float* deg_out0 = ws;                    //    50000
    float* deg_in0  = ws + 50000;            //    20000
    float* deg_out1 = ws + 70000;            //    20000
    float* deg_in1  = ws + 90000;            //     5000
    float* agg1     = ws + 95000;            //  2560000
    float* agg2     = ws + 2655000;          //  1280000
    float* x0       = ws + 3935000;          //  6400000
    float* h1       = ws + 10335000;         //  5120000  (end: 15455000 floats = 61.8 MB)

    // zero degrees + aggregation buffers (ws is poisoned 0xAA every call)
    hipMemsetAsync(ws, 0, 3935000 * sizeof(float), stream);

    deg_kernel<<<(E0 + 255) / 256, 256, 0, stream>>>(src0, dst0, src1, dst1,
                                                     deg_out0, deg_in0, deg_out1, deg_in1);
    embed_kernel<<<NSRC0, 128, 0, stream>>>(user_word, word_table, deg_out0, x0);
    scatter1_kernel<<<(E0 * 32) / 256, 256, 0, stream>>>(src0, dst0, x0, agg1);
    gemm1_kernel<<<NDST0 / 16, 256, 0, stream>>>(agg1, deg_in0, deg_out1, W1, b1, h1);
    scatter2_kernel<<<(E1 * 64) / 256, 256, 0, stream>>>(src1, dst1, h1, agg2);
    gemm2_kernel<<<(NDST1 + 15) / 16, 256, 0, stream>>>(agg2, deg_in1, W2, b2, (float*)d_out);
    labels_kernel<<<(NDST1 + 255) / 256, 256, 0, stream>>>(labels, (float*)d_out);
}

// Round 2
// 431.569 us; speedup vs baseline: 2.6823x; 2.6823x over previous
//
#include <hip/hip_runtime.h>

#define E0     300000
#define E1     75000
#define NSRC0  50000
#define NDST0  20000
#define NDST1  5000
#define EMB    128
#define HID    256
#define NOUT   16

// ---------------- int degree histograms (CSR counts + out-degrees) ----------------
__global__ void hist_kernel(const int* __restrict__ src0, const int* __restrict__ dst0,
                            const int* __restrict__ src1, const int* __restrict__ dst1,
                            int* cnt0, int* cnt1, int* degO0, int* degO1) {
    int i = blockIdx.x * blockDim.x + threadIdx.x;
    if (i < E0) {
        atomicAdd(&cnt0[dst0[i]], 1);   // in-degree graph0 (CSR bins + rsqrt scale)
        atomicAdd(&degO0[src0[i]], 1);  // out-degree graph0 (x0 scale)
    }
    if (i < E1) {
        atomicAdd(&cnt1[dst1[i]], 1);   // in-degree graph1
        atomicAdd(&degO1[src1[i]], 1);  // out-degree graph1 (h1 scale)
    }
}

// ---------------- exclusive scan (2 blocks: graph0 bins, graph1 bins) ----------------
__device__ void scan_body(const int* __restrict__ cnt, int n,
                          int* __restrict__ off, int* __restrict__ cur) {
    __shared__ int sums[256];
    int t = threadIdx.x;
    int chunk = (n + 255) / 256;
    int lo = t * chunk, hi = min(lo + chunk, n);
    int s = 0;
    for (int i = lo; i < hi; ++i) s += cnt[i];
    sums[t] = s;
    __syncthreads();
    for (int d = 1; d < 256; d <<= 1) {      // Hillis-Steele inclusive scan
        int x = (t >= d) ? sums[t - d] : 0;
        __syncthreads();
        sums[t] += x;
        __syncthreads();
    }
    int run = (t == 0) ? 0 : sums[t - 1];
    for (int i = lo; i < hi; ++i) {
        off[i] = run; cur[i] = run;
        run += cnt[i];
    }
    if (t == 255) off[n] = run;              // run == total for last thread
}

__global__ void scan_kernel(const int* cnt0, int* off0, int* cur0,
                            const int* cnt1, int* off1, int* cur1) {
    if (blockIdx.x == 0) scan_body(cnt0, NDST0, off0, cur0);
    else                 scan_body(cnt1, NDST1, off1, cur1);
}

// ---------------- bucket edges by dst (build CSR adjacency) ----------------
__global__ void bucket_kernel(const int* __restrict__ src0, const int* __restrict__ dst0,
                              const int* __restrict__ src1, const int* __restrict__ dst1,
                              int* cur0, int* cur1, int* esrc0, int* esrc1) {
    int i = blockIdx.x * blockDim.x + threadIdx.x;
    if (i < E0) {
        int p = atomicAdd(&cur0[dst0[i]], 1);
        esrc0[p] = src0[i];
    }
    if (i < E1) {
        int p = atomicAdd(&cur1[dst1[i]], 1);
        esrc1[p] = src1[i];
    }
}

// ---------------- fused embedding mean + out-degree scale ----------------
__global__ void embed_kernel(const int* __restrict__ user_word,
                             const float* __restrict__ word_table,
                             const int* __restrict__ degO0,
                             float* __restrict__ x0) {
    int node = blockIdx.x;
    int t = threadIdx.x;               // 0..127 = feature dim
    __shared__ int idx[50];
    if (t < 50) idx[t] = user_word[node * 50 + t];
    __syncthreads();
    float acc = 0.0f;
    #pragma unroll 5
    for (int w = 0; w < 50; ++w)
        acc += word_table[idx[w] * EMB + t];
    float s = rsqrtf(fmaxf((float)degO0[node], 1.0f));
    x0[node * EMB + t] = acc * 0.02f * s;   // 0.02 = 1/50 mean
}

// ---------------- layer-1 gather-aggregate: agg1[d] = rsqrt(deg)*sum x0[src] ----------------
__global__ void agg1_kernel(const int* __restrict__ off0, const int* __restrict__ esrc0,
                            const float* __restrict__ x0, float* __restrict__ agg1) {
    int d = blockIdx.x;
    int t = threadIdx.x;               // 0..127
    int lo = off0[d], hi = off0[d + 1];
    float acc = 0.0f;
    int j = lo;
    for (; j + 1 < hi; j += 2) {       // 2-edge unroll for load ILP
        int s0 = esrc0[j], s1 = esrc0[j + 1];
        acc += x0[s0 * EMB + t];
        acc += x0[s1 * EMB + t];
    }
    if (j < hi) acc += x0[esrc0[j] * EMB + t];
    float sc = rsqrtf(fmaxf((float)(hi - lo), 1.0f));
    agg1[d * EMB + t] = acc * sc;
}

// ---------------- GEMM1: h1 = relu(agg1 @ W1 + b1) * rsqrt(deg_out1) ----------------
__global__ void gemm1_kernel(const float* __restrict__ agg1,
                             const int* __restrict__ degO1,
                             const float* __restrict__ W1, const float* __restrict__ b1,
                             float* __restrict__ h1) {
    __shared__ float A[16 * 128];
    __shared__ float s_out[16];
    int row0 = blockIdx.x * 16;
    int t = threadIdx.x;
    if (t < 16)
        s_out[t] = rsqrtf(fmaxf((float)degO1[row0 + t], 1.0f));
    for (int j = t; j < 16 * 128; j += 256)
        A[j] = agg1[row0 * 128 + j];
    __syncthreads();
    float acc[16];
    #pragma unroll
    for (int r = 0; r < 16; ++r) acc[r] = 0.0f;
    for (int k = 0; k < 128; ++k) {
        float w = W1[k * 256 + t];          // coalesced across t
        #pragma unroll
        for (int r = 0; r < 16; ++r)
            acc[r] += A[r * 128 + k] * w;   // LDS broadcast
    }
    float bb = b1[t];
    #pragma unroll
    for (int r = 0; r < 16; ++r)
        h1[(row0 + r) * 256 + t] = fmaxf(acc[r] + bb, 0.0f) * s_out[r];
}

// ---------------- layer-2 gather-aggregate: agg2[d] = rsqrt(deg)*sum h1[src] ----------------
__global__ void agg2_kernel(const int* __restrict__ off1, const int* __restrict__ esrc1,
                            const float* __restrict__ h1, float* __restrict__ agg2) {
    int d = blockIdx.x;
    int t = threadIdx.x;               // 0..255
    int lo = off1[d], hi = off1[d + 1];
    float acc = 0.0f;
    int j = lo;
    for (; j + 1 < hi; j += 2) {
        int s0 = esrc1[j], s1 = esrc1[j + 1];
        acc += h1[s0 * HID + t];
        acc += h1[s1 * HID + t];
    }
    if (j < hi) acc += h1[esrc1[j] * HID + t];
    float sc = rsqrtf(fmaxf((float)(hi - lo), 1.0f));
    agg2[d * HID + t] = acc * sc;
}

// ---------------- GEMM2: out = relu(agg2 @ W2 + b2) ----------------
__global__ void gemm2_kernel(const float* __restrict__ agg2,
                             const float* __restrict__ W2, const float* __restrict__ b2,
                             float* __restrict__ out) {
    __shared__ float A[16 * 257];       // +1 pad: kills 16-way bank conflict
    __shared__ float Wl[256 * 16];
    int row0 = blockIdx.x * 16;
    int t = threadIdx.x;
    for (int j = t; j < 256 * 16; j += 256) Wl[j] = W2[j];
    for (int j = t; j < 16 * 256; j += 256) {
        int r = j >> 8, k = j & 255;
        int row = row0 + r;
        A[r * 257 + k] = (row < NDST1) ? agg2[row * 256 + k] : 0.0f;
    }
    __syncthreads();
    int r = t >> 4, c = t & 15;
    float acc = 0.0f;
    for (int k = 0; k < 256; ++k)
        acc += A[r * 257 + k] * Wl[k * 16 + c];
    int row = row0 + r;
    if (row < NDST1)
        out[row * NOUT + c] = fmaxf(acc + b2[c], 0.0f);
}

// ---------------- labels passthrough (int -> float) ----------------
__global__ void labels_kernel(const int* __restrict__ labels, float* __restrict__ out) {
    int i = blockIdx.x * blockDim.x + threadIdx.x;
    if (i < NDST1) out[NDST1 * NOUT + i] = (float)labels[i];
}

extern "C" void kernel_launch(void* const* d_in, const int* in_sizes, int n_in,
                              void* d_out, int out_size, void* d_ws, size_t ws_size,
                              hipStream_t stream) {
    const int*   user_word  = (const int*)d_in[0];
    const int*   labels     = (const int*)d_in[1];
    const int*   src0       = (const int*)d_in[2];
    const int*   dst0       = (const int*)d_in[3];
    const int*   src1       = (const int*)d_in[4];
    const int*   dst1       = (const int*)d_in[5];
    const float* word_table = (const float*)d_in[6];
    const float* W1         = (const float*)d_in[7];
    const float* b1         = (const float*)d_in[8];
    const float* W2         = (const float*)d_in[9];
    const float* b2         = (const float*)d_in[10];

    int* iws = (int*)d_ws;
    // int region (element offsets):
    int* cnt0  = iws;            // 20000  ┐
    int* cnt1  = iws + 20000;    //  5000  │ zeroed (95000 ints)
    int* degO0 = iws + 25000;    // 50000  │
    int* degO1 = iws + 75000;    // 20000  ┘
    int* off0  = iws + 95000;    // 20001
    int* off1  = iws + 115001;   //  5001
    int* cur0  = iws + 120002;   // 20000
    int* cur1  = iws + 140002;   //  5000
    int* esrc0 = iws + 145002;   // 300000
    int* esrc1 = iws + 445002;   // 75000   (end 520002; pad to 520004 for 16B align)
    // float region:
    float* x0   = (float*)(iws + 520004); // 6400000 (50000*128)
    float* agg1 = x0 + 6400000;           // 2560000 (20000*128)
    float* h1   = x0;                     // alias: x0 dead after agg1_kernel (5120000 <= 6400000)
    float* agg2 = agg1 + 2560000;         // 1280000 (5000*256)
    // total: 520004*4 + 10240000*4 = ~43 MB

    hipMemsetAsync(iws, 0, 95000 * sizeof(int), stream);

    hist_kernel<<<(E0 + 255) / 256, 256, 0, stream>>>(src0, dst0, src1, dst1,
                                                      cnt0, cnt1, degO0, degO1);
    scan_kernel<<<2, 256, 0, stream>>>(cnt0, off0, cur0, cnt1, off1, cur1);
    bucket_kernel<<<(E0 + 255) / 256, 256, 0, stream>>>(src0, dst0, src1, dst1,
                                                        cur0, cur1, esrc0, esrc1);
    embed_kernel<<<NSRC0, 128, 0, stream>>>(user_word, word_table, degO0, x0);
    agg1_kernel<<<NDST0, 128, 0, stream>>>(off0, esrc0, x0, agg1);
    gemm1_kernel<<<NDST0 / 16, 256, 0, stream>>>(agg1, degO1, W1, b1, h1);
    agg2_kernel<<<NDST1, 256, 0, stream>>>(off1, esrc1, h1, agg2);
    gemm2_kernel<<<(NDST1 + 15) / 16, 256, 0, stream>>>(agg2, W2, b2, (float*)d_out);
    labels_kernel<<<(NDST1 + 255) / 256, 256, 0, stream>>>(labels, (float*)d_out);
}

// Round 4
// 429.329 us; speedup vs baseline: 2.6963x; 1.0052x over previous
//
#include <hip/hip_runtime.h>

#define E0     300000
#define E1     75000
#define NSRC0  50000
#define NDST0  20000
#define NDST1  5000
#define EMB    128
#define HID    256
#define NOUT   16

// ---------------- int degree histograms (CSR counts + out-degrees) ----------------
__global__ void hist_kernel(const int* __restrict__ src0, const int* __restrict__ dst0,
                            const int* __restrict__ src1, const int* __restrict__ dst1,
                            int* cnt0, int* cnt1, int* degO0, int* degO1) {
    int i = blockIdx.x * blockDim.x + threadIdx.x;
    if (i < E0) {
        atomicAdd(&cnt0[dst0[i]], 1);
        atomicAdd(&degO0[src0[i]], 1);
    }
    if (i < E1) {
        atomicAdd(&cnt1[dst1[i]], 1);
        atomicAdd(&degO1[src1[i]], 1);
    }
}

// ---------------- exclusive scan (2 blocks: graph0 bins, graph1 bins) ----------------
__device__ void scan_body(const int* __restrict__ cnt, int n,
                          int* __restrict__ off, int* __restrict__ cur) {
    __shared__ int sums[256];
    int t = threadIdx.x;
    int chunk = (n + 255) / 256;
    int lo = t * chunk, hi = min(lo + chunk, n);
    int s = 0;
    for (int i = lo; i < hi; ++i) s += cnt[i];
    sums[t] = s;
    __syncthreads();
    for (int d = 1; d < 256; d <<= 1) {
        int x = (t >= d) ? sums[t - d] : 0;
        __syncthreads();
        sums[t] += x;
        __syncthreads();
    }
    int run = (t == 0) ? 0 : sums[t - 1];
    for (int i = lo; i < hi; ++i) {
        off[i] = run; cur[i] = run;
        run += cnt[i];
    }
    if (t == 255) off[n] = run;
}

__global__ void scan_kernel(const int* cnt0, int* off0, int* cur0,
                            const int* cnt1, int* off1, int* cur1) {
    if (blockIdx.x == 0) scan_body(cnt0, NDST0, off0, cur0);
    else                 scan_body(cnt1, NDST1, off1, cur1);
}

// ---------------- bucket edges by dst (build CSR adjacency) ----------------
__global__ void bucket_kernel(const int* __restrict__ src0, const int* __restrict__ dst0,
                              const int* __restrict__ src1, const int* __restrict__ dst1,
                              int* cur0, int* cur1, int* esrc0, int* esrc1) {
    int i = blockIdx.x * blockDim.x + threadIdx.x;
    if (i < E0) {
        int p = atomicAdd(&cur0[dst0[i]], 1);
        esrc0[p] = src0[i];
    }
    if (i < E1) {
        int p = atomicAdd(&cur1[dst1[i]], 1);
        esrc1[p] = src1[i];
    }
}

// ---------------- fused embedding mean + out-degree scale (float4 gather) ----------------
// block = 256 threads = 8 groups of 32 lanes; group g handles node blockIdx*8+g.
// Lane l loads word row slice [4l..4l+3] -> one dwordx4 per row per lane.
__global__ void embed_kernel(const int* __restrict__ user_word,
                             const float* __restrict__ word_table,
                             const int* __restrict__ degO0,
                             float* __restrict__ x0) {
    __shared__ int idx[8 * 50];
    int t = threadIdx.x;
    for (int j = t; j < 8 * 50; j += 256)           // FIX: stride by blockDim (was t<400 w/ 256 threads)
        idx[j] = user_word[blockIdx.x * 400 + j];
    __syncthreads();
    int g = t >> 5, l = t & 31;
    int node = blockIdx.x * 8 + g;
    const float4* wt = (const float4*)word_table;   // row = 32 float4
    float ax = 0.f, ay = 0.f, az = 0.f, aw = 0.f;
    #pragma unroll 2
    for (int w = 0; w < 50; ++w) {
        float4 v = wt[idx[g * 50 + w] * 32 + l];
        ax += v.x; ay += v.y; az += v.z; aw += v.w;
    }
    float s = rsqrtf(fmaxf((float)degO0[node], 1.0f)) * 0.02f;  // 0.02 = 1/50 mean
    float4 o; o.x = ax * s; o.y = ay * s; o.z = az * s; o.w = aw * s;
    ((float4*)x0)[node * 32 + l] = o;
}

// ---------------- layer-1 gather-aggregate (float4, 1 wave/dst) ----------------
// 64 lanes = 2 halves of 32; halves split edges; shfl-reduce; float4 store.
__global__ void agg1_kernel(const int* __restrict__ off0, const int* __restrict__ esrc0,
                            const float* __restrict__ x0, float* __restrict__ agg1) {
    int d = blockIdx.x;
    int t = threadIdx.x;               // 0..63
    int half = t >> 5, l = t & 31;
    int lo = off0[d], hi = off0[d + 1];
    const float4* x4 = (const float4*)x0;          // row = 32 float4
    float ax = 0.f, ay = 0.f, az = 0.f, aw = 0.f;
    for (int j = lo + half; j < hi; j += 2) {
        float4 v = x4[esrc0[j] * 32 + l];
        ax += v.x; ay += v.y; az += v.z; aw += v.w;
    }
    ax += __shfl_down(ax, 32); ay += __shfl_down(ay, 32);
    az += __shfl_down(az, 32); aw += __shfl_down(aw, 32);
    if (half == 0) {
        float sc = rsqrtf(fmaxf((float)(hi - lo), 1.0f));
        float4 o; o.x = ax * sc; o.y = ay * sc; o.z = az * sc; o.w = aw * sc;
        ((float4*)agg1)[d * 32 + l] = o;
    }
}

// ---------------- GEMM1: h1 = relu(agg1 @ W1 + b1) * rsqrt(deg_out1) ----------------
__global__ void gemm1_kernel(const float* __restrict__ agg1,
                             const int* __restrict__ degO1,
                             const float* __restrict__ W1, const float* __restrict__ b1,
                             float* __restrict__ h1) {
    __shared__ float A[16 * 128];
    __shared__ float s_out[16];
    int row0 = blockIdx.x * 16;
    int t = threadIdx.x;
    if (t < 16)
        s_out[t] = rsqrtf(fmaxf((float)degO1[row0 + t], 1.0f));
    for (int j = t; j < 16 * 128; j += 256)
        A[j] = agg1[row0 * 128 + j];
    __syncthreads();
    float acc[16];
    #pragma unroll
    for (int r = 0; r < 16; ++r) acc[r] = 0.0f;
    for (int k = 0; k < 128; ++k) {
        float w = W1[k * 256 + t];          // coalesced across t
        #pragma unroll
        for (int r = 0; r < 16; ++r)
            acc[r] += A[r * 128 + k] * w;   // LDS broadcast
    }
    float bb = b1[t];
    #pragma unroll
    for (int r = 0; r < 16; ++r)
        h1[(row0 + r) * 256 + t] = fmaxf(acc[r] + bb, 0.0f) * s_out[r];
}

// ---------------- layer-2 gather-aggregate (float4, 1 wave/dst, no reduce) ----------------
// row = 256 f32 = 64 lanes x float4 exactly.
__global__ void agg2_kernel(const int* __restrict__ off1, const int* __restrict__ esrc1,
                            const float* __restrict__ h1, float* __restrict__ agg2) {
    int d = blockIdx.x;
    int l = threadIdx.x;               // 0..63
    int lo = off1[d], hi = off1[d + 1];
    const float4* h4 = (const float4*)h1;          // row = 64 float4
    float ax = 0.f, ay = 0.f, az = 0.f, aw = 0.f;
    int j = lo;
    for (; j + 1 < hi; j += 2) {       // 2-edge unroll for load ILP
        float4 v0 = h4[esrc1[j] * 64 + l];
        float4 v1 = h4[esrc1[j + 1] * 64 + l];
        ax += v0.x + v1.x; ay += v0.y + v1.y;
        az += v0.z + v1.z; aw += v0.w + v1.w;
    }
    if (j < hi) {
        float4 v = h4[esrc1[j] * 64 + l];
        ax += v.x; ay += v.y; az += v.z; aw += v.w;
    }
    float sc = rsqrtf(fmaxf((float)(hi - lo), 1.0f));
    float4 o; o.x = ax * sc; o.y = ay * sc; o.z = az * sc; o.w = aw * sc;
    ((float4*)agg2)[d * 64 + l] = o;
}

// ---------------- GEMM2: out = relu(agg2 @ W2 + b2)  (+ labels passthrough) ----------------
__global__ void gemm2_kernel(const float* __restrict__ agg2,
                             const float* __restrict__ W2, const float* __restrict__ b2,
                             const int* __restrict__ labels,
                             float* __restrict__ out) {
    __shared__ float A[16 * 257];       // +1 pad: kills 16-way bank conflict
    __shared__ float Wl[256 * 16];
    int row0 = blockIdx.x * 16;
    int t = threadIdx.x;
    for (int j = t; j < 256 * 16; j += 256) Wl[j] = W2[j];
    for (int j = t; j < 16 * 256; j += 256) {
        int r = j >> 8, k = j & 255;
        int row = row0 + r;
        A[r * 257 + k] = (row < NDST1) ? agg2[row * 256 + k] : 0.0f;
    }
    __syncthreads();
    int r = t >> 4, c = t & 15;
    float acc = 0.0f;
    for (int k = 0; k < 256; ++k)
        acc += A[r * 257 + k] * Wl[k * 16 + c];
    int row = row0 + r;
    if (row < NDST1)
        out[row * NOUT + c] = fmaxf(acc + b2[c], 0.0f);
    // labels passthrough: 16 per block
    if (t < 16 && row0 + t < NDST1)
        out[NDST1 * NOUT + row0 + t] = (float)labels[row0 + t];
}

extern "C" void kernel_launch(void* const* d_in, const int* in_sizes, int n_in,
                              void* d_out, int out_size, void* d_ws, size_t ws_size,
                              hipStream_t stream) {
    const int*   user_word  = (const int*)d_in[0];
    const int*   labels     = (const int*)d_in[1];
    const int*   src0       = (const int*)d_in[2];
    const int*   dst0       = (const int*)d_in[3];
    const int*   src1       = (const int*)d_in[4];
    const int*   dst1       = (const int*)d_in[5];
    const float* word_table = (const float*)d_in[6];
    const float* W1         = (const float*)d_in[7];
    const float* b1         = (const float*)d_in[8];
    const float* W2         = (const float*)d_in[9];
    const float* b2         = (const float*)d_in[10];

    int* iws = (int*)d_ws;
    int* cnt0  = iws;            // 20000  ┐
    int* cnt1  = iws + 20000;    //  5000  │ zeroed (95000 ints)
    int* degO0 = iws + 25000;    // 50000  │
    int* degO1 = iws + 75000;    // 20000  ┘
    int* off0  = iws + 95000;    // 20001
    int* off1  = iws + 115001;   //  5001
    int* cur0  = iws + 120002;   // 20000
    int* cur1  = iws + 140002;   //  5000
    int* esrc0 = iws + 145002;   // 300000
    int* esrc1 = iws + 445002;   // 75000   (end 520002; pad to 520004 for 16B align)
    float* x0   = (float*)(iws + 520004); // 6400000 (50000*128)
    float* agg1 = x0 + 6400000;           // 2560000 (20000*128)
    float* h1   = x0;                     // alias: x0 dead after agg1_kernel
    float* agg2 = agg1 + 2560000;         // 1280000 (5000*256)

    hipMemsetAsync(iws, 0, 95000 * sizeof(int), stream);

    hist_kernel<<<(E0 + 255) / 256, 256, 0, stream>>>(src0, dst0, src1, dst1,
                                                      cnt0, cnt1, degO0, degO1);
    scan_kernel<<<2, 256, 0, stream>>>(cnt0, off0, cur0, cnt1, off1, cur1);
    bucket_kernel<<<(E0 + 255) / 256, 256, 0, stream>>>(src0, dst0, src1, dst1,
                                                        cur0, cur1, esrc0, esrc1);
    embed_kernel<<<NSRC0 / 8, 256, 0, stream>>>(user_word, word_table, degO0, x0);
    agg1_kernel<<<NDST0, 64, 0, stream>>>(off0, esrc0, x0, agg1);
    gemm1_kernel<<<NDST0 / 16, 256, 0, stream>>>(agg1, degO1, W1, b1, h1);
    agg2_kernel<<<NDST1, 64, 0, stream>>>(off1, esrc1, h1, agg2);
    gemm2_kernel<<<(NDST1 + 15) / 16, 256, 0, stream>>>(agg2, W2, b2, labels, (float*)d_out);
}